// Round 1
// baseline (598.451 us; speedup 1.0000x reference)
//
#include <hip/hip_runtime.h>

typedef __bf16 bf16_t;
typedef __bf16 bf16x8 __attribute__((ext_vector_type(8)));
typedef float floatx4 __attribute__((ext_vector_type(4)));

#define B_ 4
#define S_ 4096
#define D_ 1024
#define H_ 16
#define HD_ 64
#define M_TOT (B_ * S_)   // 16384

#define BM 128
#define BN 128
#define BK 64

__device__ __forceinline__ void async_load16(const bf16_t* g, bf16_t* l) {
  __builtin_amdgcn_global_load_lds(
      (const __attribute__((address_space(1))) void*)g,
      (__attribute__((address_space(3))) void*)l,
      16, 0, 0);
}

// ---------------- elementwise fp32 -> bf16 cast ----------------
__global__ __launch_bounds__(256) void cast_kernel(const float* __restrict__ in,
                                                   bf16_t* __restrict__ out, int n) {
  int i = (blockIdx.x * 256 + threadIdx.x) * 8;
  if (i + 8 <= n) {
    float4 a = *(const float4*)(in + i);
    float4 b = *(const float4*)(in + i + 4);
    bf16x8 o;
    o[0] = (bf16_t)a.x; o[1] = (bf16_t)a.y; o[2] = (bf16_t)a.z; o[3] = (bf16_t)a.w;
    o[4] = (bf16_t)b.x; o[5] = (bf16_t)b.y; o[6] = (bf16_t)b.z; o[7] = (bf16_t)b.w;
    *(bf16x8*)(out + i) = o;
  }
}

// ---------------- weight transpose + cast: W (K x N) -> Wt (N x K) bf16 ----------------
__global__ __launch_bounds__(256) void transpose_cast_kernel(const float* __restrict__ W,
                                                             bf16_t* __restrict__ Wt) {
  __shared__ float tile[32][33];
  int n0 = blockIdx.x * 32;
  int k0 = blockIdx.y * 32;
  int tx = threadIdx.x & 31;
  int ty = threadIdx.x >> 5;  // 0..7
  for (int r = ty; r < 32; r += 8)
    tile[r][tx] = W[(size_t)(k0 + r) * D_ + n0 + tx];
  __syncthreads();
  for (int r = ty; r < 32; r += 8)
    Wt[(size_t)(n0 + r) * D_ + k0 + tx] = (bf16_t)tile[tx][r];
}

// ---------------- bf16 MFMA GEMM: C[m][n] = sum_k A[m][k] * Bt[n][k] + bias[n] ----------------
// mode 0: bias, store bf16.  mode 1: elu(x)+1 epilogue, store bf16.  mode 2: bias, store fp32.
__global__ __launch_bounds__(256) void gemm_bt_kernel(
    const bf16_t* __restrict__ A,   // M x K
    const bf16_t* __restrict__ Bt,  // N x K
    const float* __restrict__ bias, // N
    bf16_t* __restrict__ outb,
    float* __restrict__ outf,
    int M, int N, int K, int mode) {
  __shared__ __attribute__((aligned(16))) bf16_t As[BM * BK];
  __shared__ __attribute__((aligned(16))) bf16_t Bs[BN * BK];
  const int t = threadIdx.x;
  const int w = t >> 6;
  const int lane = t & 63;
  const int row0 = blockIdx.y * BM;
  const int col0 = blockIdx.x * BN;
  const int wm = (w & 1) * 64;
  const int wn = (w >> 1) * 64;
  const int lr = lane & 15;
  const int lq = lane >> 4;

  floatx4 acc[4][4];
#pragma unroll
  for (int i = 0; i < 4; ++i)
#pragma unroll
    for (int j = 0; j < 4; ++j) acc[i][j] = (floatx4){0.f, 0.f, 0.f, 0.f};

  for (int kt = 0; kt < K; kt += BK) {
#pragma unroll
    for (int j = 0; j < 4; ++j) {
      int linear = j * 2048 + t * 8;
      int r = linear >> 6;
      int c = linear & 63;
      async_load16(&A[(size_t)(row0 + r) * K + kt + c], &As[j * 2048 + w * 512]);
      async_load16(&Bt[(size_t)(col0 + r) * K + kt + c], &Bs[j * 2048 + w * 512]);
    }
    __syncthreads();
#pragma unroll
    for (int ks = 0; ks < BK; ks += 32) {
      bf16x8 af[4], bfr[4];
#pragma unroll
      for (int i = 0; i < 4; ++i)
        af[i] = *(const bf16x8*)&As[(wm + i * 16 + lr) * BK + ks + lq * 8];
#pragma unroll
      for (int j = 0; j < 4; ++j)
        bfr[j] = *(const bf16x8*)&Bs[(wn + j * 16 + lr) * BK + ks + lq * 8];
#pragma unroll
      for (int i = 0; i < 4; ++i)
#pragma unroll
        for (int j = 0; j < 4; ++j)
          acc[i][j] = __builtin_amdgcn_mfma_f32_16x16x32_bf16(af[i], bfr[j], acc[i][j], 0, 0, 0);
    }
    __syncthreads();
  }

#pragma unroll
  for (int i = 0; i < 4; ++i) {
#pragma unroll
    for (int j = 0; j < 4; ++j) {
      int gr = row0 + wm + i * 16 + lq * 4;
      int gc = col0 + wn + j * 16 + lr;
      float bsv = bias[gc];
#pragma unroll
      for (int r = 0; r < 4; ++r) {
        float v = acc[i][j][r] + bsv;
        if (mode == 1) v = v > 0.f ? v + 1.f : __expf(v);
        if (mode == 2)
          outf[(size_t)(gr + r) * N + gc] = v;
        else
          outb[(size_t)(gr + r) * N + gc] = (bf16_t)v;
      }
    }
  }
}

// ---------------- KV summarize: KV[bh][d][e] += sum_s K[s][d]*V[s][e]; Ksum[bh][d] ----------------
__global__ __launch_bounds__(256) void kv_kernel(
    const bf16_t* __restrict__ Kf, const bf16_t* __restrict__ Vf,
    float* __restrict__ KVg, float* __restrict__ Ksumg) {
  int bh = blockIdx.x;  // b*16+h
  int sc = blockIdx.y;  // 0..7 : chunk of 512 rows of S
  int b = bh >> 4, h = bh & 15;
  __shared__ __attribute__((aligned(16))) float Ks[32][64];
  __shared__ __attribute__((aligned(16))) float Vs[32][64];
  const int t = threadIdx.x;
  const int td = (t & 15) * 4;
  const int te = (t >> 4) * 4;
  float acc[4][4] = {{0.f}};
  float ksum[4] = {0.f, 0.f, 0.f, 0.f};
  const size_t base = (size_t)b * S_ * D_ + (size_t)h * HD_;
  const int row = t >> 3;
  const int col = (t & 7) * 8;
  for (int st = 0; st < 16; ++st) {
    int s0 = sc * 512 + st * 32;
    bf16x8 k8 = *(const bf16x8*)&Kf[base + (size_t)(s0 + row) * D_ + col];
    bf16x8 v8 = *(const bf16x8*)&Vf[base + (size_t)(s0 + row) * D_ + col];
#pragma unroll
    for (int u = 0; u < 8; ++u) {
      Ks[row][col + u] = (float)k8[u];
      Vs[row][col + u] = (float)v8[u];
    }
    __syncthreads();
#pragma unroll
    for (int s = 0; s < 32; ++s) {
      const float4 kd = *(const float4*)&Ks[s][td];
      const float4 ve = *(const float4*)&Vs[s][te];
      float kdv[4] = {kd.x, kd.y, kd.z, kd.w};
      float vev[4] = {ve.x, ve.y, ve.z, ve.w};
#pragma unroll
      for (int i = 0; i < 4; ++i)
#pragma unroll
        for (int j = 0; j < 4; ++j) acc[i][j] += kdv[i] * vev[j];
      if (t < 16) {
        ksum[0] += kdv[0]; ksum[1] += kdv[1]; ksum[2] += kdv[2]; ksum[3] += kdv[3];
      }
    }
    __syncthreads();
  }
  float* kvp = KVg + (size_t)bh * 64 * 64;
#pragma unroll
  for (int i = 0; i < 4; ++i)
#pragma unroll
    for (int j = 0; j < 4; ++j) atomicAdd(&kvp[(td + i) * 64 + te + j], acc[i][j]);
  if (t < 16) {
#pragma unroll
    for (int i = 0; i < 4; ++i) atomicAdd(&Ksumg[bh * 64 + td + i], ksum[i]);
  }
}

// ---------------- attend: X[b,q,h,:] = (Q . KV) / (Q . Ksum + 1e-6) ----------------
__global__ __launch_bounds__(256) void attend_kernel(
    const bf16_t* __restrict__ Qf, const float* __restrict__ KVg,
    const float* __restrict__ Ksumg, bf16_t* __restrict__ X) {
  int bh = blockIdx.x;  // 64
  int qb = blockIdx.y;  // 64 (blocks of 64 q rows)
  int b = bh >> 4, h = bh & 15;
  __shared__ __attribute__((aligned(16))) float KVs[64 * 64];
  __shared__ __attribute__((aligned(16))) float Qs[64][64];
  __shared__ float Ksums[64];
  const int t = threadIdx.x;
  {
    const float4* src = (const float4*)(KVg + (size_t)bh * 4096);
    float4* dst = (float4*)KVs;
#pragma unroll
    for (int u = 0; u < 4; ++u) dst[u * 256 + t] = src[u * 256 + t];
  }
  if (t < 64) Ksums[t] = Ksumg[bh * 64 + t];
  {
    const int row = t >> 3;        // 0..31
    const int col = (t & 7) * 8;
    const size_t qbase = ((size_t)b * S_ + (size_t)qb * 64) * D_ + (size_t)h * HD_;
#pragma unroll
    for (int rr = 0; rr < 2; ++rr) {
      bf16x8 q8 = *(const bf16x8*)&Qf[qbase + (size_t)(rr * 32 + row) * D_ + col];
#pragma unroll
      for (int u = 0; u < 8; ++u) Qs[rr * 32 + row][col + u] = (float)q8[u];
    }
  }
  __syncthreads();
  const int tq = (t >> 4) * 4;
  const int te = (t & 15) * 4;
#pragma unroll
  for (int qq = 0; qq < 4; ++qq) {
    int q = tq + qq;
    float norm = 0.f;
    float o0 = 0.f, o1 = 0.f, o2 = 0.f, o3 = 0.f;
    for (int d = 0; d < 64; ++d) {
      float qv = Qs[q][d];
      norm += qv * Ksums[d];
      const float4 kv = *(const float4*)&KVs[d * 64 + te];
      o0 += qv * kv.x; o1 += qv * kv.y; o2 += qv * kv.z; o3 += qv * kv.w;
    }
    float inv = 1.f / (norm + 1e-6f);
    bf16_t* xp = X + ((size_t)b * S_ + (size_t)qb * 64 + q) * D_ + (size_t)h * HD_ + te;
    xp[0] = (bf16_t)(o0 * inv);
    xp[1] = (bf16_t)(o1 * inv);
    xp[2] = (bf16_t)(o2 * inv);
    xp[3] = (bf16_t)(o3 * inv);
  }
}

extern "C" void kernel_launch(void* const* d_in, const int* in_sizes, int n_in,
                              void* d_out, int out_size, void* d_ws, size_t ws_size,
                              hipStream_t stream) {
  const float* query     = (const float*)d_in[0];
  const float* key_value = (const float*)d_in[1];
  const float* Wq = (const float*)d_in[2];
  const float* bq = (const float*)d_in[3];
  const float* Wk = (const float*)d_in[4];
  const float* bk = (const float*)d_in[5];
  const float* Wv = (const float*)d_in[6];
  const float* bv = (const float*)d_in[7];
  const float* Wo = (const float*)d_in[8];
  const float* bo = (const float*)d_in[9];
  float* out = (float*)d_out;

  char* ws = (char*)d_ws;
  const size_t MB = 1024 * 1024;
  bf16_t* Aq   = (bf16_t*)(ws + 0);         // 32MB (query bf16; later reused as X)
  bf16_t* Akv  = (bf16_t*)(ws + 32 * MB);   // 32MB (key_value bf16)
  bf16_t* WqT  = (bf16_t*)(ws + 64 * MB);   // 2MB each
  bf16_t* WkT  = (bf16_t*)(ws + 66 * MB);
  bf16_t* WvT  = (bf16_t*)(ws + 68 * MB);
  bf16_t* WoT  = (bf16_t*)(ws + 70 * MB);
  bf16_t* Qf   = (bf16_t*)(ws + 72 * MB);   // 32MB
  bf16_t* Kf   = (bf16_t*)(ws + 104 * MB);  // 32MB
  bf16_t* Vf   = (bf16_t*)(ws + 136 * MB);  // 32MB
  float*  KVg  = (float*)(ws + 168 * MB);   // 1MB  (64 x 64 x 64 fp32)
  float*  Ksumg= (float*)(ws + 169 * MB);   // 16KB (64 x 64 fp32)

  const int NACT = M_TOT * D_;  // 16777216

  cast_kernel<<<NACT / 2048, 256, 0, stream>>>(query, Aq, NACT);
  cast_kernel<<<NACT / 2048, 256, 0, stream>>>(key_value, Akv, NACT);

  dim3 tgrid(32, 32);
  transpose_cast_kernel<<<tgrid, 256, 0, stream>>>(Wq, WqT);
  transpose_cast_kernel<<<tgrid, 256, 0, stream>>>(Wk, WkT);
  transpose_cast_kernel<<<tgrid, 256, 0, stream>>>(Wv, WvT);
  transpose_cast_kernel<<<tgrid, 256, 0, stream>>>(Wo, WoT);

  dim3 ggrid(D_ / BN, M_TOT / BM);  // (8, 128)
  gemm_bt_kernel<<<ggrid, 256, 0, stream>>>(Aq,  WqT, bq, Qf, nullptr, M_TOT, D_, D_, 1);
  gemm_bt_kernel<<<ggrid, 256, 0, stream>>>(Akv, WkT, bk, Kf, nullptr, M_TOT, D_, D_, 1);
  gemm_bt_kernel<<<ggrid, 256, 0, stream>>>(Akv, WvT, bv, Vf, nullptr, M_TOT, D_, D_, 0);

  hipMemsetAsync(KVg, 0, 64 * 64 * 64 * sizeof(float) + 64 * 64 * sizeof(float), stream);
  dim3 kvgrid(64, 8);
  kv_kernel<<<kvgrid, 256, 0, stream>>>(Kf, Vf, KVg, Ksumg);

  dim3 agrid(64, 64);
  attend_kernel<<<agrid, 256, 0, stream>>>(Qf, KVg, Ksumg, Aq /* X */);

  gemm_bt_kernel<<<ggrid, 256, 0, stream>>>(Aq, WoT, bo, nullptr, out, M_TOT, D_, D_, 2);
}

// Round 2
// 515.278 us; speedup vs baseline: 1.1614x; 1.1614x over previous
//
#include <hip/hip_runtime.h>

typedef __bf16 bf16_t;
typedef __bf16 bf16x8 __attribute__((ext_vector_type(8)));
typedef float floatx4 __attribute__((ext_vector_type(4)));

#define B_ 4
#define S_ 4096
#define D_ 1024
#define H_ 16
#define HD_ 64
#define M_TOT (B_ * S_)   // 16384

#define BM 128
#define BN 128
#define BK 64

__device__ __forceinline__ void async_load16(const bf16_t* g, bf16_t* l) {
  __builtin_amdgcn_global_load_lds(
      (const __attribute__((address_space(1))) void*)g,
      (__attribute__((address_space(3))) void*)l,
      16, 0, 0);
}

// ---------------- elementwise fp32 -> bf16 cast ----------------
__global__ __launch_bounds__(256) void cast_kernel(const float* __restrict__ in,
                                                   bf16_t* __restrict__ out, int n) {
  int i = (blockIdx.x * 256 + threadIdx.x) * 8;
  if (i + 8 <= n) {
    float4 a = *(const float4*)(in + i);
    float4 b = *(const float4*)(in + i + 4);
    bf16x8 o;
    o[0] = (bf16_t)a.x; o[1] = (bf16_t)a.y; o[2] = (bf16_t)a.z; o[3] = (bf16_t)a.w;
    o[4] = (bf16_t)b.x; o[5] = (bf16_t)b.y; o[6] = (bf16_t)b.z; o[7] = (bf16_t)b.w;
    *(bf16x8*)(out + i) = o;
  }
}

// ---------------- 4x weight transpose + cast: W (K x N) -> Wt (N x K) bf16 ----------------
struct WPtrs {
  const float* w0; const float* w1; const float* w2; const float* w3;
  bf16_t* t0; bf16_t* t1; bf16_t* t2; bf16_t* t3;
};

__global__ __launch_bounds__(256) void transpose_cast4_kernel(WPtrs p) {
  __shared__ float tile[32][33];
  int z = blockIdx.z;
  const float* W = z == 0 ? p.w0 : z == 1 ? p.w1 : z == 2 ? p.w2 : p.w3;
  bf16_t* Wt = z == 0 ? p.t0 : z == 1 ? p.t1 : z == 2 ? p.t2 : p.t3;
  int n0 = blockIdx.x * 32;
  int k0 = blockIdx.y * 32;
  int tx = threadIdx.x & 31;
  int ty = threadIdx.x >> 5;  // 0..7
  for (int r = ty; r < 32; r += 8)
    tile[r][tx] = W[(size_t)(k0 + r) * D_ + n0 + tx];
  __syncthreads();
  for (int r = ty; r < 32; r += 8)
    Wt[(size_t)(n0 + r) * D_ + k0 + tx] = (bf16_t)tile[tx][r];
}

// ---------------- bf16 MFMA GEMM: C[m][n] = sum_k A[m][k] * Bt[n][k] + bias[n] ----------------
// mode 0: bias, store bf16.  mode 1: elu(x)+1 epilogue, store bf16.  mode 2: bias, store fp32.
__global__ __launch_bounds__(256) void gemm_bt_kernel(
    const bf16_t* __restrict__ A,   // M x K
    const bf16_t* __restrict__ Bt,  // N x K
    const float* __restrict__ bias, // N
    bf16_t* __restrict__ outb,
    float* __restrict__ outf,
    int M, int N, int K, int mode) {
  __shared__ __attribute__((aligned(16))) bf16_t As[BM * BK];
  __shared__ __attribute__((aligned(16))) bf16_t Bs[BN * BK];
  const int t = threadIdx.x;
  const int w = t >> 6;
  const int lane = t & 63;
  const int row0 = blockIdx.y * BM;
  const int col0 = blockIdx.x * BN;
  const int wm = (w & 1) * 64;
  const int wn = (w >> 1) * 64;
  const int lr = lane & 15;
  const int lq = lane >> 4;

  floatx4 acc[4][4];
#pragma unroll
  for (int i = 0; i < 4; ++i)
#pragma unroll
    for (int j = 0; j < 4; ++j) acc[i][j] = (floatx4){0.f, 0.f, 0.f, 0.f};

  for (int kt = 0; kt < K; kt += BK) {
#pragma unroll
    for (int j = 0; j < 4; ++j) {
      int linear = j * 2048 + t * 8;
      int r = linear >> 6;
      int c = linear & 63;
      async_load16(&A[(size_t)(row0 + r) * K + kt + c], &As[j * 2048 + w * 512]);
      async_load16(&Bt[(size_t)(col0 + r) * K + kt + c], &Bs[j * 2048 + w * 512]);
    }
    __syncthreads();
#pragma unroll
    for (int ks = 0; ks < BK; ks += 32) {
      bf16x8 af[4], bfr[4];
#pragma unroll
      for (int i = 0; i < 4; ++i)
        af[i] = *(const bf16x8*)&As[(wm + i * 16 + lr) * BK + ks + lq * 8];
#pragma unroll
      for (int j = 0; j < 4; ++j)
        bfr[j] = *(const bf16x8*)&Bs[(wn + j * 16 + lr) * BK + ks + lq * 8];
#pragma unroll
      for (int i = 0; i < 4; ++i)
#pragma unroll
        for (int j = 0; j < 4; ++j)
          acc[i][j] = __builtin_amdgcn_mfma_f32_16x16x32_bf16(af[i], bfr[j], acc[i][j], 0, 0, 0);
    }
    __syncthreads();
  }

#pragma unroll
  for (int i = 0; i < 4; ++i) {
#pragma unroll
    for (int j = 0; j < 4; ++j) {
      int gr = row0 + wm + i * 16 + lq * 4;
      int gc = col0 + wn + j * 16 + lr;
      float bsv = bias[gc];
#pragma unroll
      for (int r = 0; r < 4; ++r) {
        float v = acc[i][j][r] + bsv;
        if (mode == 1) v = v > 0.f ? v + 1.f : __expf(v);
        if (mode == 2)
          outf[(size_t)(gr + r) * N + gc] = v;
        else
          outb[(size_t)(gr + r) * N + gc] = (bf16_t)v;
      }
    }
  }
}

// ---------------- KV summarize: KV[bh][d][e] += sum_s K[s][d]*V[s][e]; Ksum[bh][d] ----------------
__global__ __launch_bounds__(256) void kv_kernel(
    const bf16_t* __restrict__ Kf, const bf16_t* __restrict__ Vf,
    float* __restrict__ KVg, float* __restrict__ Ksumg) {
  int bh = blockIdx.x;  // b*16+h
  int sc = blockIdx.y;  // 0..7 : chunk of 512 rows of S
  int b = bh >> 4, h = bh & 15;
  __shared__ __attribute__((aligned(16))) float Ks[32][64];
  __shared__ __attribute__((aligned(16))) float Vs[32][64];
  const int t = threadIdx.x;
  const int td = (t & 15) * 4;
  const int te = (t >> 4) * 4;
  float acc[4][4] = {{0.f}};
  float ksum[4] = {0.f, 0.f, 0.f, 0.f};
  const size_t base = (size_t)b * S_ * D_ + (size_t)h * HD_;
  const int row = t >> 3;
  const int col = (t & 7) * 8;
  for (int st = 0; st < 16; ++st) {
    int s0 = sc * 512 + st * 32;
    bf16x8 k8 = *(const bf16x8*)&Kf[base + (size_t)(s0 + row) * D_ + col];
    bf16x8 v8 = *(const bf16x8*)&Vf[base + (size_t)(s0 + row) * D_ + col];
#pragma unroll
    for (int u = 0; u < 8; ++u) {
      Ks[row][col + u] = (float)k8[u];
      Vs[row][col + u] = (float)v8[u];
    }
    __syncthreads();
#pragma unroll
    for (int s = 0; s < 32; ++s) {
      const float4 kd = *(const float4*)&Ks[s][td];
      const float4 ve = *(const float4*)&Vs[s][te];
      float kdv[4] = {kd.x, kd.y, kd.z, kd.w};
      float vev[4] = {ve.x, ve.y, ve.z, ve.w};
#pragma unroll
      for (int i = 0; i < 4; ++i)
#pragma unroll
        for (int j = 0; j < 4; ++j) acc[i][j] += kdv[i] * vev[j];
      if (t < 16) {
        ksum[0] += kdv[0]; ksum[1] += kdv[1]; ksum[2] += kdv[2]; ksum[3] += kdv[3];
      }
    }
    __syncthreads();
  }
  float* kvp = KVg + (size_t)bh * 64 * 64;
#pragma unroll
  for (int i = 0; i < 4; ++i)
#pragma unroll
    for (int j = 0; j < 4; ++j) atomicAdd(&kvp[(td + i) * 64 + te + j], acc[i][j]);
  if (t < 16) {
#pragma unroll
    for (int i = 0; i < 4; ++i) atomicAdd(&Ksumg[bh * 64 + td + i], ksum[i]);
  }
}

// ---------------- KV transpose-cast: KVg fp32 [bh][d][e] -> KVtb bf16 [bh][e][d] ----------------
__global__ __launch_bounds__(256) void kvt_kernel(const float* __restrict__ KVg,
                                                  bf16_t* __restrict__ KVtb) {
  int bh = blockIdx.x;
  __shared__ float tile[64 * 65];
  const float* src = KVg + (size_t)bh * 4096;
  const int t = threadIdx.x;
#pragma unroll
  for (int u = 0; u < 4; ++u) {
    int idx = u * 1024 + t * 4;  // d = idx>>6, e = idx&63
    float4 v = *(const float4*)&src[idx];
    int d = idx >> 6, e = idx & 63;
    tile[d * 65 + e + 0] = v.x;
    tile[d * 65 + e + 1] = v.y;
    tile[d * 65 + e + 2] = v.z;
    tile[d * 65 + e + 3] = v.w;
  }
  __syncthreads();
  int e = t >> 2, d0 = (t & 3) * 16;
  bf16_t* dst = KVtb + (size_t)bh * 4096 + e * 64 + d0;
  bf16x8 o1, o2;
#pragma unroll
  for (int u = 0; u < 8; ++u) o1[u] = (bf16_t)tile[(d0 + u) * 65 + e];
#pragma unroll
  for (int u = 0; u < 8; ++u) o2[u] = (bf16_t)tile[(d0 + 8 + u) * 65 + e];
  *(bf16x8*)dst = o1;
  *(bf16x8*)(dst + 8) = o2;
}

// ---------------- attend (MFMA): X[b,q,h,:] = (Q . KV) / (Q . Ksum + 1e-6) ----------------
// Block: 256 q-rows of one (b,h). Wave w: rows w*64..w*64+63, full N=64.
__global__ __launch_bounds__(256) void attend_mfma_kernel(
    const bf16_t* __restrict__ Qf, const bf16_t* __restrict__ KVtb,
    const float* __restrict__ Ksumg, bf16_t* __restrict__ X) {
  __shared__ __attribute__((aligned(16))) bf16_t As[256 * 64];  // 32KB
  __shared__ __attribute__((aligned(16))) bf16_t Bs[64 * 64];   // 8KB
  const int t = threadIdx.x;
  const int w = t >> 6;
  const int lane = t & 63;
  const int lr = lane & 15;
  const int lq = lane >> 4;
  const int bh = blockIdx.y;
  const int b = bh >> 4, h = bh & 15;
  const int q0 = blockIdx.x * 256;
  const size_t qbase = ((size_t)b * S_ + q0) * D_ + (size_t)h * HD_;

  // stage Q rows (wave w covers rows w*64 .. w*64+63; 8 issues of 8 rows)
#pragma unroll
  for (int it = 0; it < 8; ++it) {
    int r = w * 64 + it * 8 + (lane >> 3);
    int c = (lane & 7) * 8;
    async_load16(&Qf[qbase + (size_t)r * D_ + c], &As[(w * 64 + it * 8) * 64]);
  }
  // stage KV^T (64x64 bf16 = 8KB, 2 issues of 512 elements per wave)
#pragma unroll
  for (int it = 0; it < 2; ++it) {
    int off = w * 1024 + it * 512;
    async_load16(&KVtb[(size_t)bh * 4096 + off + lane * 8], &Bs[off]);
  }

  // norm B fragments: row n=0 holds Ksum (bf16), rows 1..15 zero
  bf16x8 bn[2];
#pragma unroll
  for (int ks = 0; ks < 2; ++ks) {
    bf16x8 z;
#pragma unroll
    for (int u = 0; u < 8; ++u) z[u] = (bf16_t)0.f;
    if (lr == 0) {
      const float* kp = &Ksumg[bh * 64 + ks * 32 + lq * 8];
      float4 k1 = *(const float4*)kp;
      float4 k2 = *(const float4*)(kp + 4);
      z[0] = (bf16_t)k1.x; z[1] = (bf16_t)k1.y; z[2] = (bf16_t)k1.z; z[3] = (bf16_t)k1.w;
      z[4] = (bf16_t)k2.x; z[5] = (bf16_t)k2.y; z[6] = (bf16_t)k2.z; z[7] = (bf16_t)k2.w;
    }
    bn[ks] = z;
  }

  floatx4 acc[4][4];
  floatx4 accn[4];
#pragma unroll
  for (int i = 0; i < 4; ++i) {
    accn[i] = (floatx4){0.f, 0.f, 0.f, 0.f};
#pragma unroll
    for (int j = 0; j < 4; ++j) acc[i][j] = (floatx4){0.f, 0.f, 0.f, 0.f};
  }

  __syncthreads();

#pragma unroll
  for (int ks = 0; ks < 2; ++ks) {
    bf16x8 af[4], bfr[4];
#pragma unroll
    for (int i = 0; i < 4; ++i)
      af[i] = *(const bf16x8*)&As[(w * 64 + i * 16 + lr) * 64 + ks * 32 + lq * 8];
#pragma unroll
    for (int j = 0; j < 4; ++j)
      bfr[j] = *(const bf16x8*)&Bs[(j * 16 + lr) * 64 + ks * 32 + lq * 8];
#pragma unroll
    for (int i = 0; i < 4; ++i) {
#pragma unroll
      for (int j = 0; j < 4; ++j)
        acc[i][j] = __builtin_amdgcn_mfma_f32_16x16x32_bf16(af[i], bfr[j], acc[i][j], 0, 0, 0);
      accn[i] = __builtin_amdgcn_mfma_f32_16x16x32_bf16(af[i], bn[ks], accn[i], 0, 0, 0);
    }
  }

  // epilogue: normalize and store bf16
#pragma unroll
  for (int i = 0; i < 4; ++i) {
    int rowb = q0 + w * 64 + i * 16 + lq * 4;
#pragma unroll
    for (int r = 0; r < 4; ++r) {
      float nr = __shfl(accn[i][r], lane & 48);  // norm lives on lane lr==0 of each lq group
      float inv = 1.f / (nr + 1e-6f);
      size_t rb = ((size_t)b * S_ + rowb + r) * D_ + (size_t)h * HD_;
#pragma unroll
      for (int j = 0; j < 4; ++j)
        X[rb + j * 16 + lr] = (bf16_t)(acc[i][j][r] * inv);
    }
  }
}

extern "C" void kernel_launch(void* const* d_in, const int* in_sizes, int n_in,
                              void* d_out, int out_size, void* d_ws, size_t ws_size,
                              hipStream_t stream) {
  const float* query     = (const float*)d_in[0];
  const float* key_value = (const float*)d_in[1];
  const float* Wq = (const float*)d_in[2];
  const float* bq = (const float*)d_in[3];
  const float* Wk = (const float*)d_in[4];
  const float* bk = (const float*)d_in[5];
  const float* Wv = (const float*)d_in[6];
  const float* bv = (const float*)d_in[7];
  const float* Wo = (const float*)d_in[8];
  const float* bo = (const float*)d_in[9];
  float* out = (float*)d_out;

  char* ws = (char*)d_ws;
  const size_t MB = 1024 * 1024;
  bf16_t* Aq   = (bf16_t*)(ws + 0);         // 32MB (query bf16; later reused as X)
  bf16_t* Akv  = (bf16_t*)(ws + 32 * MB);   // 32MB (key_value bf16; later reused as KVtb)
  bf16_t* WqT  = (bf16_t*)(ws + 64 * MB);   // 2MB each
  bf16_t* WkT  = (bf16_t*)(ws + 66 * MB);
  bf16_t* WvT  = (bf16_t*)(ws + 68 * MB);
  bf16_t* WoT  = (bf16_t*)(ws + 70 * MB);
  bf16_t* Qf   = (bf16_t*)(ws + 72 * MB);   // 32MB
  bf16_t* Kf   = (bf16_t*)(ws + 104 * MB);  // 32MB
  bf16_t* Vf   = (bf16_t*)(ws + 136 * MB);  // 32MB
  float*  KVg  = (float*)(ws + 168 * MB);   // 1MB  (64 x 64 x 64 fp32)
  float*  Ksumg= (float*)(ws + 169 * MB);   // 16KB (64 x 64 fp32)
  bf16_t* KVtb = Akv;                       // reuse dead Akv region (512KB needed)

  const int NACT = M_TOT * D_;  // 16777216

  cast_kernel<<<NACT / 2048, 256, 0, stream>>>(query, Aq, NACT);
  cast_kernel<<<NACT / 2048, 256, 0, stream>>>(key_value, Akv, NACT);

  WPtrs wp = {Wq, Wk, Wv, Wo, WqT, WkT, WvT, WoT};
  dim3 tgrid(32, 32, 4);
  transpose_cast4_kernel<<<tgrid, 256, 0, stream>>>(wp);

  dim3 ggrid(D_ / BN, M_TOT / BM);  // (8, 128)
  gemm_bt_kernel<<<ggrid, 256, 0, stream>>>(Aq,  WqT, bq, Qf, nullptr, M_TOT, D_, D_, 1);
  gemm_bt_kernel<<<ggrid, 256, 0, stream>>>(Akv, WkT, bk, Kf, nullptr, M_TOT, D_, D_, 1);
  gemm_bt_kernel<<<ggrid, 256, 0, stream>>>(Akv, WvT, bv, Vf, nullptr, M_TOT, D_, D_, 0);

  hipMemsetAsync(KVg, 0, 64 * 64 * 64 * sizeof(float) + 64 * 64 * sizeof(float), stream);
  dim3 kvgrid(64, 8);
  kv_kernel<<<kvgrid, 256, 0, stream>>>(Kf, Vf, KVg, Ksumg);

  kvt_kernel<<<64, 256, 0, stream>>>(KVg, KVtb);

  dim3 agrid(S_ / 256, 64);  // (16, 64)
  attend_mfma_kernel<<<agrid, 256, 0, stream>>>(Qf, KVtb, Ksumg, Aq /* X */);

  gemm_bt_kernel<<<ggrid, 256, 0, stream>>>(Aq, WoT, bo, nullptr, out, M_TOT, D_, D_, 2);
}

// Round 3
// 470.129 us; speedup vs baseline: 1.2730x; 1.0960x over previous
//
#include <hip/hip_runtime.h>

typedef __bf16 bf16_t;
typedef __bf16 bf16x2 __attribute__((ext_vector_type(2)));
typedef __bf16 bf16x8 __attribute__((ext_vector_type(8)));
typedef float floatx4 __attribute__((ext_vector_type(4)));

#define B_ 4
#define S_ 4096
#define D_ 1024
#define H_ 16
#define HD_ 64
#define M_TOT (B_ * S_)   // 16384

#define BM 128
#define BN 128
#define BK 64

__device__ __forceinline__ void async_load16(const bf16_t* g, bf16_t* l) {
  __builtin_amdgcn_global_load_lds(
      (const __attribute__((address_space(1))) void*)g,
      (__attribute__((address_space(3))) void*)l,
      16, 0, 0);
}

// ---------------- elementwise fp32 -> bf16 cast ----------------
__global__ __launch_bounds__(256) void cast_kernel(const float* __restrict__ in,
                                                   bf16_t* __restrict__ out, int n) {
  int i = (blockIdx.x * 256 + threadIdx.x) * 8;
  if (i + 8 <= n) {
    float4 a = *(const float4*)(in + i);
    float4 b = *(const float4*)(in + i + 4);
    bf16x8 o;
    o[0] = (bf16_t)a.x; o[1] = (bf16_t)a.y; o[2] = (bf16_t)a.z; o[3] = (bf16_t)a.w;
    o[4] = (bf16_t)b.x; o[5] = (bf16_t)b.y; o[6] = (bf16_t)b.z; o[7] = (bf16_t)b.w;
    *(bf16x8*)(out + i) = o;
  }
}

// ---------------- 4x weight transpose + cast: W (K x N) -> Wt (N x K) bf16 ----------------
struct WPtrs {
  const float* w0; const float* w1; const float* w2; const float* w3;
  bf16_t* t0; bf16_t* t1; bf16_t* t2; bf16_t* t3;
};

__global__ __launch_bounds__(256) void transpose_cast4_kernel(WPtrs p) {
  __shared__ float tile[32][33];
  int z = blockIdx.z;
  const float* W = z == 0 ? p.w0 : z == 1 ? p.w1 : z == 2 ? p.w2 : p.w3;
  bf16_t* Wt = z == 0 ? p.t0 : z == 1 ? p.t1 : z == 2 ? p.t2 : p.t3;
  int n0 = blockIdx.x * 32;
  int k0 = blockIdx.y * 32;
  int tx = threadIdx.x & 31;
  int ty = threadIdx.x >> 5;  // 0..7
  for (int r = ty; r < 32; r += 8)
    tile[r][tx] = W[(size_t)(k0 + r) * D_ + n0 + tx];
  __syncthreads();
  for (int r = ty; r < 32; r += 8)
    Wt[(size_t)(n0 + r) * D_ + k0 + tx] = (bf16_t)tile[tx][r];
}

// ---------------- bf16 MFMA GEMM: C[m][n] = sum_k A[m][k] * Bt[n][k] + bias[n] ----------------
// mode 0: bias, store bf16.  mode 1: elu(x)+1, store bf16.  mode 2: bias, store fp32.
// mode 3: fused dual output: n<1024 -> elu+1 into outb (stride 1024), n>=1024 -> bias2 into outb2.
__global__ __launch_bounds__(256) void gemm_bt_kernel(
    const bf16_t* __restrict__ A,    // M x K
    const bf16_t* __restrict__ Bt,   // N x K
    const float* __restrict__ bias,  // N (first 1024 in mode 3)
    const float* __restrict__ bias2, // mode 3: second 1024
    bf16_t* __restrict__ outb,
    bf16_t* __restrict__ outb2,
    float* __restrict__ outf,
    int M, int N, int K, int mode) {
  __shared__ __attribute__((aligned(16))) bf16_t As[BM * BK];
  __shared__ __attribute__((aligned(16))) bf16_t Bs[BN * BK];
  const int t = threadIdx.x;
  const int w = t >> 6;
  const int lane = t & 63;

  // XCD-aware swizzle: blocks sharing an A m-tile land consecutively on one XCD.
  const int L = blockIdx.y * gridDim.x + blockIdx.x;
  const int nxl2 = 31 - __clz(gridDim.x);       // gridDim.x is a power of 2
  const int xcd = L & 7;
  const int slot = L >> 3;
  const int mt = xcd * (gridDim.y >> 3) + (slot >> nxl2);
  const int nt = slot & ((1 << nxl2) - 1);
  const int row0 = mt * BM;
  const int col0 = nt * BN;

  const int wm = (w & 1) * 64;
  const int wn = (w >> 1) * 64;
  const int lr = lane & 15;
  const int lq = lane >> 4;

  floatx4 acc[4][4];
#pragma unroll
  for (int i = 0; i < 4; ++i)
#pragma unroll
    for (int j = 0; j < 4; ++j) acc[i][j] = (floatx4){0.f, 0.f, 0.f, 0.f};

  for (int kt = 0; kt < K; kt += BK) {
#pragma unroll
    for (int j = 0; j < 4; ++j) {
      int linear = j * 2048 + t * 8;
      int r = linear >> 6;
      int c = linear & 63;
      async_load16(&A[(size_t)(row0 + r) * K + kt + c], &As[j * 2048 + w * 512]);
      async_load16(&Bt[(size_t)(col0 + r) * K + kt + c], &Bs[j * 2048 + w * 512]);
    }
    __syncthreads();
#pragma unroll
    for (int ks = 0; ks < BK; ks += 32) {
      bf16x8 af[4], bfr[4];
#pragma unroll
      for (int i = 0; i < 4; ++i)
        af[i] = *(const bf16x8*)&As[(wm + i * 16 + lr) * BK + ks + lq * 8];
#pragma unroll
      for (int j = 0; j < 4; ++j)
        bfr[j] = *(const bf16x8*)&Bs[(wn + j * 16 + lr) * BK + ks + lq * 8];
#pragma unroll
      for (int i = 0; i < 4; ++i)
#pragma unroll
        for (int j = 0; j < 4; ++j)
          acc[i][j] = __builtin_amdgcn_mfma_f32_16x16x32_bf16(af[i], bfr[j], acc[i][j], 0, 0, 0);
    }
    __syncthreads();
  }

#pragma unroll
  for (int i = 0; i < 4; ++i) {
#pragma unroll
    for (int j = 0; j < 4; ++j) {
      int gr = row0 + wm + i * 16 + lq * 4;
      int gc = col0 + wn + j * 16 + lr;
      if (mode == 3) {
        if (gc < 1024) {
          float bsv = bias[gc];
#pragma unroll
          for (int r = 0; r < 4; ++r) {
            float v = acc[i][j][r] + bsv;
            v = v > 0.f ? v + 1.f : __expf(v);
            outb[(size_t)(gr + r) * 1024 + gc] = (bf16_t)v;
          }
        } else {
          float bsv = bias2[gc - 1024];
#pragma unroll
          for (int r = 0; r < 4; ++r) {
            float v = acc[i][j][r] + bsv;
            outb2[(size_t)(gr + r) * 1024 + (gc - 1024)] = (bf16_t)v;
          }
        }
      } else {
        float bsv = bias[gc];
#pragma unroll
        for (int r = 0; r < 4; ++r) {
          float v = acc[i][j][r] + bsv;
          if (mode == 1) v = v > 0.f ? v + 1.f : __expf(v);
          if (mode == 2)
            outf[(size_t)(gr + r) * N + gc] = v;
          else
            outb[(size_t)(gr + r) * N + gc] = (bf16_t)v;
        }
      }
    }
  }
}

// ---------------- KV summarize (MFMA): KVt[bh][e][d] += sum_s V[s][e]*K[s][d]; Ksum[bh][d] ----------------
// grid (64 bh, 8 s-chunks of 512); per block: C' = V^T * K  (64e x 64d), Ksum via ones-row A-frag.
#define KVP 68  // LDS row stride (elems) for transposed tiles
__global__ __launch_bounds__(256) void kv_mfma_kernel(
    const bf16_t* __restrict__ Kf, const bf16_t* __restrict__ Vf,
    float* __restrict__ KVtg, float* __restrict__ Ksumg) {
  __shared__ __attribute__((aligned(16))) bf16_t Kt[64 * KVP];  // [d][s]
  __shared__ __attribute__((aligned(16))) bf16_t Vt[64 * KVP];  // [e][s]
  const int t = threadIdx.x;
  const int w = t >> 6, lane = t & 63;
  const int lr = lane & 15, lq = lane >> 4;
  const int bh = blockIdx.x, sc = blockIdx.y;
  const int b = bh >> 4, h = bh & 15;
  const size_t base = (size_t)b * S_ * D_ + (size_t)h * HD_;
  const int p = t >> 3;          // row-pair 0..31
  const int c0 = (t & 7) * 8;    // feature col 0..56

  floatx4 acc[4], accn[4];
#pragma unroll
  for (int j = 0; j < 4; ++j) {
    acc[j] = (floatx4){0.f, 0.f, 0.f, 0.f};
    accn[j] = (floatx4){0.f, 0.f, 0.f, 0.f};
  }
  bf16x8 ones;
#pragma unroll
  for (int u = 0; u < 8; ++u) ones[u] = (bf16_t)(lr == 0 ? 1.f : 0.f);

  for (int st = 0; st < 8; ++st) {  // 8 tiles x 64 s = 512 s
    int s0 = sc * 512 + st * 64;
    bf16x8 ka = *(const bf16x8*)&Kf[base + (size_t)(s0 + 2 * p) * D_ + c0];
    bf16x8 kb = *(const bf16x8*)&Kf[base + (size_t)(s0 + 2 * p + 1) * D_ + c0];
    bf16x8 va = *(const bf16x8*)&Vf[base + (size_t)(s0 + 2 * p) * D_ + c0];
    bf16x8 vb = *(const bf16x8*)&Vf[base + (size_t)(s0 + 2 * p + 1) * D_ + c0];
    __syncthreads();  // previous iter's reads done before overwriting LDS
#pragma unroll
    for (int u = 0; u < 8; ++u) {
      *(bf16x2*)&Kt[(c0 + u) * KVP + 2 * p] = (bf16x2){ka[u], kb[u]};
      *(bf16x2*)&Vt[(c0 + u) * KVP + 2 * p] = (bf16x2){va[u], vb[u]};
    }
    __syncthreads();
#pragma unroll
    for (int ks = 0; ks < 2; ++ks) {
      bf16x8 af = *(const bf16x8*)&Vt[(w * 16 + lr) * KVP + ks * 32 + lq * 8];
      bf16x8 bf_[4];
#pragma unroll
      for (int j = 0; j < 4; ++j)
        bf_[j] = *(const bf16x8*)&Kt[(j * 16 + lr) * KVP + ks * 32 + lq * 8];
#pragma unroll
      for (int j = 0; j < 4; ++j)
        acc[j] = __builtin_amdgcn_mfma_f32_16x16x32_bf16(af, bf_[j], acc[j], 0, 0, 0);
      if (w == 0) {
#pragma unroll
        for (int j = 0; j < 4; ++j)
          accn[j] = __builtin_amdgcn_mfma_f32_16x16x32_bf16(ones, bf_[j], accn[j], 0, 0, 0);
      }
    }
  }
  float* kvp = KVtg + (size_t)bh * 4096;
#pragma unroll
  for (int j = 0; j < 4; ++j)
#pragma unroll
    for (int r = 0; r < 4; ++r)
      atomicAdd(&kvp[(w * 16 + lq * 4 + r) * 64 + j * 16 + lr], acc[j][r]);
  if (w == 0 && lq == 0) {
#pragma unroll
    for (int j = 0; j < 4; ++j)
      atomicAdd(&Ksumg[bh * 64 + j * 16 + lr], accn[j][0]);
  }
}

// ---------------- attend (MFMA): X[b,q,h,:] = (Q . KV) / (Q . Ksum + 1e-6) ----------------
__global__ __launch_bounds__(256) void attend_mfma_kernel(
    const bf16_t* __restrict__ Qf, const float* __restrict__ KVtg,
    const float* __restrict__ Ksumg, bf16_t* __restrict__ X) {
  __shared__ __attribute__((aligned(16))) bf16_t As[256 * 64];  // 32KB
  __shared__ __attribute__((aligned(16))) bf16_t Bs[64 * 64];   // 8KB
  const int t = threadIdx.x;
  const int w = t >> 6;
  const int lane = t & 63;
  const int lr = lane & 15;
  const int lq = lane >> 4;
  const int bh = blockIdx.y;
  const int b = bh >> 4, h = bh & 15;
  const int q0 = blockIdx.x * 256;
  const size_t qbase = ((size_t)b * S_ + q0) * D_ + (size_t)h * HD_;

  // stage Q rows via async LDS DMA
#pragma unroll
  for (int it = 0; it < 8; ++it) {
    int r = w * 64 + it * 8 + (lane >> 3);
    int c = (lane & 7) * 8;
    async_load16(&Qf[qbase + (size_t)r * D_ + c], &As[(w * 64 + it * 8) * 64]);
  }
  // stage KV^T: fp32 -> bf16 cast (KVtg is [e][d] row-major = exactly Bt layout)
  {
    const float* src = KVtg + (size_t)bh * 4096;
    int i0 = t * 16;
    float4 f0 = *(const float4*)(src + i0);
    float4 f1 = *(const float4*)(src + i0 + 4);
    float4 f2 = *(const float4*)(src + i0 + 8);
    float4 f3 = *(const float4*)(src + i0 + 12);
    bf16x8 o1, o2;
    o1[0] = (bf16_t)f0.x; o1[1] = (bf16_t)f0.y; o1[2] = (bf16_t)f0.z; o1[3] = (bf16_t)f0.w;
    o1[4] = (bf16_t)f1.x; o1[5] = (bf16_t)f1.y; o1[6] = (bf16_t)f1.z; o1[7] = (bf16_t)f1.w;
    o2[0] = (bf16_t)f2.x; o2[1] = (bf16_t)f2.y; o2[2] = (bf16_t)f2.z; o2[3] = (bf16_t)f2.w;
    o2[4] = (bf16_t)f3.x; o2[5] = (bf16_t)f3.y; o2[6] = (bf16_t)f3.z; o2[7] = (bf16_t)f3.w;
    *(bf16x8*)&Bs[i0] = o1;
    *(bf16x8*)&Bs[i0 + 8] = o2;
  }

  // norm B fragments: row n=0 holds Ksum (bf16), rows 1..15 zero
  bf16x8 bn[2];
#pragma unroll
  for (int ks = 0; ks < 2; ++ks) {
    bf16x8 z;
#pragma unroll
    for (int u = 0; u < 8; ++u) z[u] = (bf16_t)0.f;
    if (lr == 0) {
      const float* kp = &Ksumg[bh * 64 + ks * 32 + lq * 8];
      float4 k1 = *(const float4*)kp;
      float4 k2 = *(const float4*)(kp + 4);
      z[0] = (bf16_t)k1.x; z[1] = (bf16_t)k1.y; z[2] = (bf16_t)k1.z; z[3] = (bf16_t)k1.w;
      z[4] = (bf16_t)k2.x; z[5] = (bf16_t)k2.y; z[6] = (bf16_t)k2.z; z[7] = (bf16_t)k2.w;
    }
    bn[ks] = z;
  }

  floatx4 acc[4][4];
  floatx4 accn[4];
#pragma unroll
  for (int i = 0; i < 4; ++i) {
    accn[i] = (floatx4){0.f, 0.f, 0.f, 0.f};
#pragma unroll
    for (int j = 0; j < 4; ++j) acc[i][j] = (floatx4){0.f, 0.f, 0.f, 0.f};
  }

  __syncthreads();

#pragma unroll
  for (int ks = 0; ks < 2; ++ks) {
    bf16x8 af[4], bfr[4];
#pragma unroll
    for (int i = 0; i < 4; ++i)
      af[i] = *(const bf16x8*)&As[(w * 64 + i * 16 + lr) * 64 + ks * 32 + lq * 8];
#pragma unroll
    for (int j = 0; j < 4; ++j)
      bfr[j] = *(const bf16x8*)&Bs[(j * 16 + lr) * 64 + ks * 32 + lq * 8];
#pragma unroll
    for (int i = 0; i < 4; ++i) {
#pragma unroll
      for (int j = 0; j < 4; ++j)
        acc[i][j] = __builtin_amdgcn_mfma_f32_16x16x32_bf16(af[i], bfr[j], acc[i][j], 0, 0, 0);
      accn[i] = __builtin_amdgcn_mfma_f32_16x16x32_bf16(af[i], bn[ks], accn[i], 0, 0, 0);
    }
  }

  // epilogue: normalize and store bf16
#pragma unroll
  for (int i = 0; i < 4; ++i) {
    int rowb = q0 + w * 64 + i * 16 + lq * 4;
#pragma unroll
    for (int r = 0; r < 4; ++r) {
      float nr = __shfl(accn[i][r], lane & 48);  // norm lives on lane lr==0 of each lq group
      float inv = 1.f / (nr + 1e-6f);
      size_t rb = ((size_t)b * S_ + rowb + r) * D_ + (size_t)h * HD_;
#pragma unroll
      for (int j = 0; j < 4; ++j)
        X[rb + j * 16 + lr] = (bf16_t)(acc[i][j][r] * inv);
    }
  }
}

extern "C" void kernel_launch(void* const* d_in, const int* in_sizes, int n_in,
                              void* d_out, int out_size, void* d_ws, size_t ws_size,
                              hipStream_t stream) {
  const float* query     = (const float*)d_in[0];
  const float* key_value = (const float*)d_in[1];
  const float* Wq = (const float*)d_in[2];
  const float* bq = (const float*)d_in[3];
  const float* Wk = (const float*)d_in[4];
  const float* bk = (const float*)d_in[5];
  const float* Wv = (const float*)d_in[6];
  const float* bv = (const float*)d_in[7];
  const float* Wo = (const float*)d_in[8];
  const float* bo = (const float*)d_in[9];
  float* out = (float*)d_out;

  char* ws = (char*)d_ws;
  const size_t MB = 1024 * 1024;
  bf16_t* Aq   = (bf16_t*)(ws + 0);         // 32MB (query bf16; later reused as X)
  bf16_t* Akv  = (bf16_t*)(ws + 32 * MB);   // 32MB (key_value bf16)
  bf16_t* WqT  = (bf16_t*)(ws + 64 * MB);   // 2MB each
  bf16_t* WkT  = (bf16_t*)(ws + 66 * MB);   // WkT and WvT are ADJACENT -> fused N=2048 B matrix
  bf16_t* WvT  = (bf16_t*)(ws + 68 * MB);
  bf16_t* WoT  = (bf16_t*)(ws + 70 * MB);
  bf16_t* Qf   = (bf16_t*)(ws + 72 * MB);   // 32MB
  bf16_t* Kf   = (bf16_t*)(ws + 104 * MB);  // 32MB
  bf16_t* Vf   = (bf16_t*)(ws + 136 * MB);  // 32MB
  float*  KVtg = (float*)(ws + 168 * MB);   // 1MB  (64 x [e][d] fp32)
  float*  Ksumg= (float*)(ws + 169 * MB);   // 16KB

  const int NACT = M_TOT * D_;  // 16777216

  cast_kernel<<<NACT / 2048, 256, 0, stream>>>(query, Aq, NACT);
  cast_kernel<<<NACT / 2048, 256, 0, stream>>>(key_value, Akv, NACT);

  WPtrs wp = {Wq, Wk, Wv, Wo, WqT, WkT, WvT, WoT};
  dim3 tgrid(32, 32, 4);
  transpose_cast4_kernel<<<tgrid, 256, 0, stream>>>(wp);

  dim3 ggrid(D_ / BN, M_TOT / BM);    // (8, 128)
  dim3 ggrid2(2 * D_ / BN, M_TOT / BM);  // (16, 128) fused K+V

  gemm_bt_kernel<<<ggrid, 256, 0, stream>>>(Aq, WqT, bq, nullptr, Qf, nullptr, nullptr,
                                            M_TOT, D_, D_, 1);
  gemm_bt_kernel<<<ggrid2, 256, 0, stream>>>(Akv, WkT, bk, bv, Kf, Vf, nullptr,
                                             M_TOT, 2 * D_, D_, 3);

  hipMemsetAsync(KVtg, 0, 64 * 64 * 64 * sizeof(float) + 64 * 64 * sizeof(float), stream);
  dim3 kvgrid(64, 8);
  kv_mfma_kernel<<<kvgrid, 256, 0, stream>>>(Kf, Vf, KVtg, Ksumg);

  dim3 agrid(S_ / 256, 64);  // (16, 64)
  attend_mfma_kernel<<<agrid, 256, 0, stream>>>(Qf, KVtg, Ksumg, Aq /* X */);

  gemm_bt_kernel<<<ggrid, 256, 0, stream>>>(Aq, WoT, bo, nullptr, nullptr, nullptr, out,
                                            M_TOT, D_, D_, 2);
}

// Round 5
// 419.250 us; speedup vs baseline: 1.4274x; 1.1214x over previous
//
#include <hip/hip_runtime.h>

typedef __bf16 bf16_t;
typedef __bf16 bf16x2 __attribute__((ext_vector_type(2)));
typedef __bf16 bf16x8 __attribute__((ext_vector_type(8)));
typedef float floatx4 __attribute__((ext_vector_type(4)));

#define B_ 4
#define S_ 4096
#define D_ 1024
#define H_ 16
#define HD_ 64
#define M_TOT (B_ * S_)   // 16384

#define BM 128
#define BN 128
#define BK 64

__device__ __forceinline__ void async_load16(const bf16_t* g, bf16_t* l) {
  __builtin_amdgcn_global_load_lds(
      (const __attribute__((address_space(1))) void*)g,
      (__attribute__((address_space(3))) void*)l,
      16, 0, 0);
}

// ---------------- elementwise fp32 -> bf16 cast ----------------
__global__ __launch_bounds__(256) void cast_kernel(const float* __restrict__ in,
                                                   bf16_t* __restrict__ out, int n) {
  int i = (blockIdx.x * 256 + threadIdx.x) * 8;
  if (i + 8 <= n) {
    float4 a = *(const float4*)(in + i);
    float4 b = *(const float4*)(in + i + 4);
    bf16x8 o;
    o[0] = (bf16_t)a.x; o[1] = (bf16_t)a.y; o[2] = (bf16_t)a.z; o[3] = (bf16_t)a.w;
    o[4] = (bf16_t)b.x; o[5] = (bf16_t)b.y; o[6] = (bf16_t)b.z; o[7] = (bf16_t)b.w;
    *(bf16x8*)(out + i) = o;
  }
}

// ---------------- 4x weight transpose + cast: W (K x N) -> Wt (N x K) bf16 ----------------
struct WPtrs {
  const float* w0; const float* w1; const float* w2; const float* w3;
  bf16_t* t0; bf16_t* t1; bf16_t* t2; bf16_t* t3;
};

__global__ __launch_bounds__(256) void transpose_cast4_kernel(WPtrs p) {
  __shared__ float tile[32][33];
  int z = blockIdx.z;
  const float* W = z == 0 ? p.w0 : z == 1 ? p.w1 : z == 2 ? p.w2 : p.w3;
  bf16_t* Wt = z == 0 ? p.t0 : z == 1 ? p.t1 : z == 2 ? p.t2 : p.t3;
  int n0 = blockIdx.x * 32;
  int k0 = blockIdx.y * 32;
  int tx = threadIdx.x & 31;
  int ty = threadIdx.x >> 5;  // 0..7
  for (int r = ty; r < 32; r += 8)
    tile[r][tx] = W[(size_t)(k0 + r) * D_ + n0 + tx];
  __syncthreads();
  for (int r = ty; r < 32; r += 8)
    Wt[(size_t)(n0 + r) * D_ + k0 + tx] = (bf16_t)tile[tx][r];
}

// ---------------- bf16 MFMA GEMM: C[m][n] = sum_k A[m][k] * Bt[n][k] + bias[n] ----------------
// LDS tiles are XOR-swizzled at 16B-chunk granularity: chunk slot (r, cc) holds
// global chunk (r, cc ^ (r&7)) -> fragment reads are bank-conflict-free (2-way max).
// mode 0: bias, store bf16.  mode 1: elu(x)+1, store bf16.  mode 2: bias, store fp32.
// mode 3: fused dual output: n<1024 -> elu+1 into outb (stride 1024), n>=1024 -> bias2 into outb2.
__global__ __launch_bounds__(256) void gemm_bt_kernel(
    const bf16_t* __restrict__ A,    // M x K
    const bf16_t* __restrict__ Bt,   // N x K
    const float* __restrict__ bias,  // N (first 1024 in mode 3)
    const float* __restrict__ bias2, // mode 3: second 1024
    bf16_t* __restrict__ outb,
    bf16_t* __restrict__ outb2,
    float* __restrict__ outf,
    int M, int N, int K, int mode) {
  __shared__ __attribute__((aligned(16))) bf16_t As[BM * BK];
  __shared__ __attribute__((aligned(16))) bf16_t Bs[BN * BK];
  const int t = threadIdx.x;
  const int w = t >> 6;
  const int lane = t & 63;

  // XCD-aware swizzle: blocks sharing an A m-tile land consecutively on one XCD.
  const int L = blockIdx.y * gridDim.x + blockIdx.x;
  const int nxl2 = 31 - __clz(gridDim.x);       // gridDim.x is a power of 2
  const int xcd = L & 7;
  const int slot = L >> 3;
  const int mt = xcd * (gridDim.y >> 3) + (slot >> nxl2);
  const int nt = slot & ((1 << nxl2) - 1);
  const int row0 = mt * BM;
  const int col0 = nt * BN;

  const int wm = (w & 1) * 64;
  const int wn = (w >> 1) * 64;
  const int lr = lane & 15;
  const int lq = lane >> 4;
  const int rx = lr & 7;  // fragment-read XOR key (row & 7)

  floatx4 acc[4][4];
#pragma unroll
  for (int i = 0; i < 4; ++i)
#pragma unroll
    for (int j = 0; j < 4; ++j) acc[i][j] = (floatx4){0.f, 0.f, 0.f, 0.f};

  for (int kt = 0; kt < K; kt += BK) {
#pragma unroll
    for (int j = 0; j < 4; ++j) {
      int s = j * 256 + t;                       // 16B-chunk slot in tile
      int r = s >> 3;                            // tile row
      int cs = (((s & 7) ^ (r & 7)) << 3);       // swizzled source column (elems)
      async_load16(&A[(size_t)(row0 + r) * K + kt + cs], &As[j * 2048 + w * 512]);
      async_load16(&Bt[(size_t)(col0 + r) * K + kt + cs], &Bs[j * 2048 + w * 512]);
    }
    __syncthreads();
#pragma unroll
    for (int ks = 0; ks < BK; ks += 32) {
      const int go = ((lq + (ks >> 3)) ^ rx) << 3;  // swizzled chunk offset (elems)
      bf16x8 af[4], bfr[4];
#pragma unroll
      for (int i = 0; i < 4; ++i)
        af[i] = *(const bf16x8*)&As[(wm + i * 16 + lr) * BK + go];
#pragma unroll
      for (int j = 0; j < 4; ++j)
        bfr[j] = *(const bf16x8*)&Bs[(wn + j * 16 + lr) * BK + go];
#pragma unroll
      for (int i = 0; i < 4; ++i)
#pragma unroll
        for (int j = 0; j < 4; ++j)
          acc[i][j] = __builtin_amdgcn_mfma_f32_16x16x32_bf16(af[i], bfr[j], acc[i][j], 0, 0, 0);
    }
    __syncthreads();
  }

#pragma unroll
  for (int i = 0; i < 4; ++i) {
#pragma unroll
    for (int j = 0; j < 4; ++j) {
      int gr = row0 + wm + i * 16 + lq * 4;
      int gc = col0 + wn + j * 16 + lr;
      if (mode == 3) {
        if (gc < 1024) {
          float bsv = bias[gc];
#pragma unroll
          for (int r = 0; r < 4; ++r) {
            float v = acc[i][j][r] + bsv;
            v = v > 0.f ? v + 1.f : __expf(v);
            outb[(size_t)(gr + r) * 1024 + gc] = (bf16_t)v;
          }
        } else {
          float bsv = bias2[gc - 1024];
#pragma unroll
          for (int r = 0; r < 4; ++r) {
            float v = acc[i][j][r] + bsv;
            outb2[(size_t)(gr + r) * 1024 + (gc - 1024)] = (bf16_t)v;
          }
        }
      } else {
        float bsv = bias[gc];
#pragma unroll
        for (int r = 0; r < 4; ++r) {
          float v = acc[i][j][r] + bsv;
          if (mode == 1) v = v > 0.f ? v + 1.f : __expf(v);
          if (mode == 2)
            outf[(size_t)(gr + r) * N + gc] = v;
          else
            outb[(size_t)(gr + r) * N + gc] = (bf16_t)v;
        }
      }
    }
  }
}

// ---------------- KV summarize (MFMA): KVt[bh][e][d] += sum_s V[s][e]*K[s][d]; Ksum[bh][d] ----------------
#define KVP 68  // LDS row stride (elems) for transposed tiles
__global__ __launch_bounds__(256) void kv_mfma_kernel(
    const bf16_t* __restrict__ Kf, const bf16_t* __restrict__ Vf,
    float* __restrict__ KVtg, float* __restrict__ Ksumg) {
  __shared__ __attribute__((aligned(16))) bf16_t Kt[64 * KVP];  // [d][s]
  __shared__ __attribute__((aligned(16))) bf16_t Vt[64 * KVP];  // [e][s]
  const int t = threadIdx.x;
  const int w = t >> 6, lane = t & 63;
  const int lr = lane & 15, lq = lane >> 4;
  const int bh = blockIdx.x, sc = blockIdx.y;
  const int b = bh >> 4, h = bh & 15;
  const size_t base = (size_t)b * S_ * D_ + (size_t)h * HD_;
  const int p = t >> 3;          // row-pair 0..31
  const int c0 = (t & 7) * 8;    // feature col 0..56

  floatx4 acc[4], accn[4];
#pragma unroll
  for (int j = 0; j < 4; ++j) {
    acc[j] = (floatx4){0.f, 0.f, 0.f, 0.f};
    accn[j] = (floatx4){0.f, 0.f, 0.f, 0.f};
  }
  bf16x8 ones;
#pragma unroll
  for (int u = 0; u < 8; ++u) ones[u] = (bf16_t)(lr == 0 ? 1.f : 0.f);

  for (int st = 0; st < 8; ++st) {  // 8 tiles x 64 s = 512 s
    int s0 = sc * 512 + st * 64;
    bf16x8 ka = *(const bf16x8*)&Kf[base + (size_t)(s0 + 2 * p) * D_ + c0];
    bf16x8 kb = *(const bf16x8*)&Kf[base + (size_t)(s0 + 2 * p + 1) * D_ + c0];
    bf16x8 va = *(const bf16x8*)&Vf[base + (size_t)(s0 + 2 * p) * D_ + c0];
    bf16x8 vb = *(const bf16x8*)&Vf[base + (size_t)(s0 + 2 * p + 1) * D_ + c0];
    __syncthreads();  // previous iter's reads done before overwriting LDS
#pragma unroll
    for (int u = 0; u < 8; ++u) {
      *(bf16x2*)&Kt[(c0 + u) * KVP + 2 * p] = (bf16x2){ka[u], kb[u]};
      *(bf16x2*)&Vt[(c0 + u) * KVP + 2 * p] = (bf16x2){va[u], vb[u]};
    }
    __syncthreads();
#pragma unroll
    for (int ks = 0; ks < 2; ++ks) {
      bf16x8 af = *(const bf16x8*)&Vt[(w * 16 + lr) * KVP + ks * 32 + lq * 8];
      bf16x8 bf_[4];
#pragma unroll
      for (int j = 0; j < 4; ++j)
        bf_[j] = *(const bf16x8*)&Kt[(j * 16 + lr) * KVP + ks * 32 + lq * 8];
#pragma unroll
      for (int j = 0; j < 4; ++j)
        acc[j] = __builtin_amdgcn_mfma_f32_16x16x32_bf16(af, bf_[j], acc[j], 0, 0, 0);
      if (w == 0) {
#pragma unroll
        for (int j = 0; j < 4; ++j)
          accn[j] = __builtin_amdgcn_mfma_f32_16x16x32_bf16(ones, bf_[j], accn[j], 0, 0, 0);
      }
    }
  }
  float* kvp = KVtg + (size_t)bh * 4096;
#pragma unroll
  for (int j = 0; j < 4; ++j)
#pragma unroll
    for (int r = 0; r < 4; ++r)
      atomicAdd(&kvp[(w * 16 + lq * 4 + r) * 64 + j * 16 + lr], acc[j][r]);
  if (w == 0 && lq == 0) {
#pragma unroll
    for (int j = 0; j < 4; ++j)
      atomicAdd(&Ksumg[bh * 64 + j * 16 + lr], accn[j][0]);
  }
}

// ---------------- attend (MFMA): X[b,q,h,:] = (Q . KV) / (Q . Ksum + 1e-6) ----------------
// As/Bs XOR-swizzled at 16B-chunk granularity like gemm_bt_kernel.
__global__ __launch_bounds__(256) void attend_mfma_kernel(
    const bf16_t* __restrict__ Qf, const float* __restrict__ KVtg,
    const float* __restrict__ Ksumg, bf16_t* __restrict__ X) {
  __shared__ __attribute__((aligned(16))) bf16_t As[256 * 64];  // 32KB
  __shared__ __attribute__((aligned(16))) bf16_t Bs[64 * 64];   // 8KB
  const int t = threadIdx.x;
  const int w = t >> 6;
  const int lane = t & 63;
  const int lr = lane & 15;
  const int lq = lane >> 4;
  const int rx = lr & 7;
  const int bh = blockIdx.y;
  const int b = bh >> 4, h = bh & 15;
  const int q0 = blockIdx.x * 256;
  const size_t qbase = ((size_t)b * S_ + q0) * D_ + (size_t)h * HD_;

  // stage Q rows via async LDS DMA (swizzled source chunk)
  {
    const int r8 = lane >> 3;
    const int cs = (((lane & 7) ^ (r8 & 7)) << 3);
#pragma unroll
    for (int it = 0; it < 8; ++it) {
      int r = w * 64 + it * 8 + r8;
      async_load16(&Qf[qbase + (size_t)r * D_ + cs], &As[(w * 64 + it * 8) * 64]);
    }
  }
  // stage KV^T: fp32 -> bf16 cast (KVtg is [e][d] row-major = exactly Bt layout), swizzled store
  {
    const float* src = KVtg + (size_t)bh * 4096;
    int i0 = t * 16;
    float4 f0 = *(const float4*)(src + i0);
    float4 f1 = *(const float4*)(src + i0 + 4);
    float4 f2 = *(const float4*)(src + i0 + 8);
    float4 f3 = *(const float4*)(src + i0 + 12);
    bf16x8 o1, o2;
    o1[0] = (bf16_t)f0.x; o1[1] = (bf16_t)f0.y; o1[2] = (bf16_t)f0.z; o1[3] = (bf16_t)f0.w;
    o1[4] = (bf16_t)f1.x; o1[5] = (bf16_t)f1.y; o1[6] = (bf16_t)f1.z; o1[7] = (bf16_t)f1.w;
    o2[0] = (bf16_t)f2.x; o2[1] = (bf16_t)f2.y; o2[2] = (bf16_t)f2.z; o2[3] = (bf16_t)f2.w;
    o2[4] = (bf16_t)f3.x; o2[5] = (bf16_t)f3.y; o2[6] = (bf16_t)f3.z; o2[7] = (bf16_t)f3.w;
    int r = t >> 2;
    int cc = (t & 3) * 2;
    int rxw = r & 7;
    *(bf16x8*)&Bs[r * 64 + ((cc ^ rxw) << 3)] = o1;
    *(bf16x8*)&Bs[r * 64 + (((cc + 1) ^ rxw) << 3)] = o2;
  }

  // norm B fragments: row n=0 holds Ksum (bf16), rows 1..15 zero
  bf16x8 bn[2];
#pragma unroll
  for (int ks = 0; ks < 2; ++ks) {
    bf16x8 z;
#pragma unroll
    for (int u = 0; u < 8; ++u) z[u] = (bf16_t)0.f;
    if (lr == 0) {
      const float* kp = &Ksumg[bh * 64 + ks * 32 + lq * 8];
      float4 k1 = *(const float4*)kp;
      float4 k2 = *(const float4*)(kp + 4);
      z[0] = (bf16_t)k1.x; z[1] = (bf16_t)k1.y; z[2] = (bf16_t)k1.z; z[3] = (bf16_t)k1.w;
      z[4] = (bf16_t)k2.x; z[5] = (bf16_t)k2.y; z[6] = (bf16_t)k2.z; z[7] = (bf16_t)k2.w;
    }
    bn[ks] = z;
  }

  floatx4 acc[4][4];
  floatx4 accn[4];
#pragma unroll
  for (int i = 0; i < 4; ++i) {
    accn[i] = (floatx4){0.f, 0.f, 0.f, 0.f};
#pragma unroll
    for (int j = 0; j < 4; ++j) acc[i][j] = (floatx4){0.f, 0.f, 0.f, 0.f};
  }

  __syncthreads();

#pragma unroll
  for (int ks = 0; ks < 2; ++ks) {
    // ks is a STEP INDEX here (chunk offset = ks*4), unlike gemm where ks is an elem offset
    const int go = ((lq + ks * 4) ^ rx) << 3;
    bf16x8 af[4], bfr[4];
#pragma unroll
    for (int i = 0; i < 4; ++i)
      af[i] = *(const bf16x8*)&As[(w * 64 + i * 16 + lr) * 64 + go];
#pragma unroll
    for (int j = 0; j < 4; ++j)
      bfr[j] = *(const bf16x8*)&Bs[(j * 16 + lr) * 64 + go];
#pragma unroll
    for (int i = 0; i < 4; ++i) {
#pragma unroll
      for (int j = 0; j < 4; ++j)
        acc[i][j] = __builtin_amdgcn_mfma_f32_16x16x32_bf16(af[i], bfr[j], acc[i][j], 0, 0, 0);
      accn[i] = __builtin_amdgcn_mfma_f32_16x16x32_bf16(af[i], bn[ks], accn[i], 0, 0, 0);
    }
  }

  // epilogue: normalize and store bf16
#pragma unroll
  for (int i = 0; i < 4; ++i) {
    int rowb = q0 + w * 64 + i * 16 + lq * 4;
#pragma unroll
    for (int r = 0; r < 4; ++r) {
      float nr = __shfl(accn[i][r], lane & 48);  // norm lives on lane lr==0 of each lq group
      float inv = 1.f / (nr + 1e-6f);
      size_t rb = ((size_t)b * S_ + rowb + r) * D_ + (size_t)h * HD_;
#pragma unroll
      for (int j = 0; j < 4; ++j)
        X[rb + j * 16 + lr] = (bf16_t)(acc[i][j][r] * inv);
    }
  }
}

extern "C" void kernel_launch(void* const* d_in, const int* in_sizes, int n_in,
                              void* d_out, int out_size, void* d_ws, size_t ws_size,
                              hipStream_t stream) {
  const float* query     = (const float*)d_in[0];
  const float* key_value = (const float*)d_in[1];
  const float* Wq = (const float*)d_in[2];
  const float* bq = (const float*)d_in[3];
  const float* Wk = (const float*)d_in[4];
  const float* bk = (const float*)d_in[5];
  const float* Wv = (const float*)d_in[6];
  const float* bv = (const float*)d_in[7];
  const float* Wo = (const float*)d_in[8];
  const float* bo = (const float*)d_in[9];
  float* out = (float*)d_out;

  char* ws = (char*)d_ws;
  const size_t MB = 1024 * 1024;
  bf16_t* Aq   = (bf16_t*)(ws + 0);         // 32MB (query bf16; later reused as X)
  bf16_t* Akv  = (bf16_t*)(ws + 32 * MB);   // 32MB (key_value bf16)
  bf16_t* WqT  = (bf16_t*)(ws + 64 * MB);   // 2MB each
  bf16_t* WkT  = (bf16_t*)(ws + 66 * MB);   // WkT and WvT are ADJACENT -> fused N=2048 B matrix
  bf16_t* WvT  = (bf16_t*)(ws + 68 * MB);
  bf16_t* WoT  = (bf16_t*)(ws + 70 * MB);
  bf16_t* Qf   = (bf16_t*)(ws + 72 * MB);   // 32MB
  bf16_t* Kf   = (bf16_t*)(ws + 104 * MB);  // 32MB
  bf16_t* Vf   = (bf16_t*)(ws + 136 * MB);  // 32MB
  float*  KVtg = (float*)(ws + 168 * MB);   // 1MB  (64 x [e][d] fp32)
  float*  Ksumg= (float*)(ws + 169 * MB);   // 16KB

  const int NACT = M_TOT * D_;  // 16777216

  cast_kernel<<<NACT / 2048, 256, 0, stream>>>(query, Aq, NACT);
  cast_kernel<<<NACT / 2048, 256, 0, stream>>>(key_value, Akv, NACT);

  WPtrs wp = {Wq, Wk, Wv, Wo, WqT, WkT, WvT, WoT};
  dim3 tgrid(32, 32, 4);
  transpose_cast4_kernel<<<tgrid, 256, 0, stream>>>(wp);

  dim3 ggrid(D_ / BN, M_TOT / BM);       // (8, 128)
  dim3 ggrid2(2 * D_ / BN, M_TOT / BM);  // (16, 128) fused K+V

  gemm_bt_kernel<<<ggrid, 256, 0, stream>>>(Aq, WqT, bq, nullptr, Qf, nullptr, nullptr,
                                            M_TOT, D_, D_, 1);
  gemm_bt_kernel<<<ggrid2, 256, 0, stream>>>(Akv, WkT, bk, bv, Kf, Vf, nullptr,
                                             M_TOT, 2 * D_, D_, 3);

  hipMemsetAsync(KVtg, 0, 64 * 64 * 64 * sizeof(float) + 64 * 64 * sizeof(float), stream);
  dim3 kvgrid(64, 8);
  kv_mfma_kernel<<<kvgrid, 256, 0, stream>>>(Kf, Vf, KVtg, Ksumg);

  dim3 agrid(S_ / 256, 64);  // (16, 64)
  attend_mfma_kernel<<<agrid, 256, 0, stream>>>(Qf, KVtg, Ksumg, Aq /* X */);

  gemm_bt_kernel<<<ggrid, 256, 0, stream>>>(Aq, WoT, bo, nullptr, nullptr, nullptr, out,
                                            M_TOT, D_, D_, 2);
}

// Round 6
// 410.507 us; speedup vs baseline: 1.4578x; 1.0213x over previous
//
#include <hip/hip_runtime.h>

typedef __bf16 bf16_t;
typedef __bf16 bf16x2 __attribute__((ext_vector_type(2)));
typedef __bf16 bf16x8 __attribute__((ext_vector_type(8)));
typedef float floatx4 __attribute__((ext_vector_type(4)));

#define B_ 4
#define S_ 4096
#define D_ 1024
#define H_ 16
#define HD_ 64
#define M_TOT (B_ * S_)   // 16384

#define BM 128
#define BN 128
#define BK 64

__device__ __forceinline__ void async_load16(const bf16_t* g, bf16_t* l) {
  __builtin_amdgcn_global_load_lds(
      (const __attribute__((address_space(1))) void*)g,
      (__attribute__((address_space(3))) void*)l,
      16, 0, 0);
}

// ---------------- fused prep: casts + weight transposes + workspace zeroing ----------------
// 1D grid, block-uniform branches:
//   [0,8192)      : cast query fp32 -> Aq bf16
//   [8192,16384)  : cast key_value fp32 -> Akv bf16
//   [16384,20480) : 4x transpose-cast W (KxN fp32) -> Wt (NxK bf16)
//   [20480,20740) : zero KVtg + Ksumg (1MB + 16KB contiguous)
struct PrepArgs {
  const float* q; const float* kv;
  bf16_t* aq; bf16_t* akv;
  const float* w0; const float* w1; const float* w2; const float* w3;
  bf16_t* t0; bf16_t* t1; bf16_t* t2; bf16_t* t3;
  float* zbase;
};

__global__ __launch_bounds__(256) void prep_kernel(PrepArgs p) {
  __shared__ float tile[32][33];
  const int bid = blockIdx.x;
  const int t = threadIdx.x;
  if (bid < 16384) {
    const float* in = bid < 8192 ? p.q : p.kv;
    bf16_t* out = bid < 8192 ? p.aq : p.akv;
    int i = ((bid & 8191) * 256 + t) * 8;
    float4 a = *(const float4*)(in + i);
    float4 b = *(const float4*)(in + i + 4);
    bf16x8 o;
    o[0] = (bf16_t)a.x; o[1] = (bf16_t)a.y; o[2] = (bf16_t)a.z; o[3] = (bf16_t)a.w;
    o[4] = (bf16_t)b.x; o[5] = (bf16_t)b.y; o[6] = (bf16_t)b.z; o[7] = (bf16_t)b.w;
    *(bf16x8*)(out + i) = o;
  } else if (bid < 20480) {
    int idx = bid - 16384;
    int z = idx >> 10;
    int rem = idx & 1023;
    const float* W = z == 0 ? p.w0 : z == 1 ? p.w1 : z == 2 ? p.w2 : p.w3;
    bf16_t* Wt = z == 0 ? p.t0 : z == 1 ? p.t1 : z == 2 ? p.t2 : p.t3;
    int n0 = (rem & 31) * 32;
    int k0 = (rem >> 5) * 32;
    int tx = t & 31;
    int ty = t >> 5;  // 0..7
    for (int r = ty; r < 32; r += 8)
      tile[r][tx] = W[(size_t)(k0 + r) * D_ + n0 + tx];
    __syncthreads();
    for (int r = ty; r < 32; r += 8)
      Wt[(size_t)(n0 + r) * D_ + k0 + tx] = (bf16_t)tile[tx][r];
  } else {
    int idx = bid - 20480;  // 0..259 ; 260*256 float4 = 1MB + 16KB
    ((float4*)p.zbase)[idx * 256 + t] = (float4){0.f, 0.f, 0.f, 0.f};
  }
}

// ---------------- merged Q/K/V projection GEMM (MFMA, XOR-swizzled LDS) ----------------
// 3072 blocks: per XCD 384 slots; mt = xcd*16 + slot/24, nt = slot%24.
// nt<8 : C=Aq*WqT', elu+1 -> Qf.  nt>=8 : C=Akv*Wkv', n<1024 elu+1 -> Kf, else bias -> Vf.
struct ProjArgs {
  const bf16_t* Aq; const bf16_t* Akv;
  const bf16_t* WqT; const bf16_t* WkvT;  // WkvT = 2048 x 1024 (Wk rows then Wv rows)
  const float* bq; const float* bk; const float* bv;
  bf16_t* Qf; bf16_t* Kf; bf16_t* Vf;
};

__global__ __launch_bounds__(256) void proj_kernel(ProjArgs p) {
  __shared__ __attribute__((aligned(16))) bf16_t As[BM * BK];
  __shared__ __attribute__((aligned(16))) bf16_t Bs[BN * BK];
  const int t = threadIdx.x;
  const int w = t >> 6;
  const int lane = t & 63;

  const unsigned L = blockIdx.x;
  const unsigned xcd = L & 7;
  const unsigned slot = L >> 3;          // 0..383
  const unsigned mt = xcd * 16 + slot / 24u;
  const unsigned nt = slot % 24u;
  const int row0 = mt * BM;
  const bool isQ = nt < 8;
  const bf16_t* A  = isQ ? p.Aq : p.Akv;
  const bf16_t* Bt = isQ ? p.WqT : p.WkvT;
  const int col0 = (isQ ? nt : nt - 8) * BN;

  const int wm = (w & 1) * 64;
  const int wn = (w >> 1) * 64;
  const int lr = lane & 15;
  const int lq = lane >> 4;
  const int rx = lr & 7;  // fragment-read XOR key (row & 7)

  floatx4 acc[4][4];
#pragma unroll
  for (int i = 0; i < 4; ++i)
#pragma unroll
    for (int j = 0; j < 4; ++j) acc[i][j] = (floatx4){0.f, 0.f, 0.f, 0.f};

  for (int kt = 0; kt < D_; kt += BK) {
#pragma unroll
    for (int j = 0; j < 4; ++j) {
      int s = j * 256 + t;                       // 16B-chunk slot in tile
      int r = s >> 3;                            // tile row
      int cs = (((s & 7) ^ (r & 7)) << 3);       // swizzled source column (elems)
      async_load16(&A[(size_t)(row0 + r) * D_ + kt + cs], &As[j * 2048 + w * 512]);
      async_load16(&Bt[(size_t)(col0 + r) * D_ + kt + cs], &Bs[j * 2048 + w * 512]);
    }
    __syncthreads();
#pragma unroll
    for (int ks = 0; ks < BK; ks += 32) {
      const int go = ((lq + (ks >> 3)) ^ rx) << 3;  // swizzled chunk offset (elems)
      bf16x8 af[4], bfr[4];
#pragma unroll
      for (int i = 0; i < 4; ++i)
        af[i] = *(const bf16x8*)&As[(wm + i * 16 + lr) * BK + go];
#pragma unroll
      for (int j = 0; j < 4; ++j)
        bfr[j] = *(const bf16x8*)&Bs[(wn + j * 16 + lr) * BK + go];
#pragma unroll
      for (int i = 0; i < 4; ++i)
#pragma unroll
        for (int j = 0; j < 4; ++j)
          acc[i][j] = __builtin_amdgcn_mfma_f32_16x16x32_bf16(af[i], bfr[j], acc[i][j], 0, 0, 0);
    }
    __syncthreads();
  }

#pragma unroll
  for (int i = 0; i < 4; ++i) {
#pragma unroll
    for (int j = 0; j < 4; ++j) {
      int gr = row0 + wm + i * 16 + lq * 4;
      int gc = col0 + wn + j * 16 + lr;
      if (isQ) {
        float bsv = p.bq[gc];
#pragma unroll
        for (int r = 0; r < 4; ++r) {
          float v = acc[i][j][r] + bsv;
          v = v > 0.f ? v + 1.f : __expf(v);
          p.Qf[(size_t)(gr + r) * 1024 + gc] = (bf16_t)v;
        }
      } else if (gc < 1024) {
        float bsv = p.bk[gc];
#pragma unroll
        for (int r = 0; r < 4; ++r) {
          float v = acc[i][j][r] + bsv;
          v = v > 0.f ? v + 1.f : __expf(v);
          p.Kf[(size_t)(gr + r) * 1024 + gc] = (bf16_t)v;
        }
      } else {
        float bsv = p.bv[gc - 1024];
#pragma unroll
        for (int r = 0; r < 4; ++r) {
          float v = acc[i][j][r] + bsv;
          p.Vf[(size_t)(gr + r) * 1024 + (gc - 1024)] = (bf16_t)v;
        }
      }
    }
  }
}

// ---------------- output GEMM: out[m][n] = sum_k X[m][k] * WoT[n][k] + bo[n] (fp32 out) ----------------
__global__ __launch_bounds__(256) void gemm_out_kernel(
    const bf16_t* __restrict__ A,    // M x K
    const bf16_t* __restrict__ Bt,   // N x K
    const float* __restrict__ bias,
    float* __restrict__ outf) {
  __shared__ __attribute__((aligned(16))) bf16_t As[BM * BK];
  __shared__ __attribute__((aligned(16))) bf16_t Bs[BN * BK];
  const int t = threadIdx.x;
  const int w = t >> 6;
  const int lane = t & 63;

  // XCD-aware swizzle (grid (8,128))
  const int L = blockIdx.y * gridDim.x + blockIdx.x;
  const int xcd = L & 7;
  const int slot = L >> 3;
  const int mt = xcd * 16 + (slot >> 3);
  const int nt = slot & 7;
  const int row0 = mt * BM;
  const int col0 = nt * BN;

  const int wm = (w & 1) * 64;
  const int wn = (w >> 1) * 64;
  const int lr = lane & 15;
  const int lq = lane >> 4;
  const int rx = lr & 7;

  floatx4 acc[4][4];
#pragma unroll
  for (int i = 0; i < 4; ++i)
#pragma unroll
    for (int j = 0; j < 4; ++j) acc[i][j] = (floatx4){0.f, 0.f, 0.f, 0.f};

  for (int kt = 0; kt < D_; kt += BK) {
#pragma unroll
    for (int j = 0; j < 4; ++j) {
      int s = j * 256 + t;
      int r = s >> 3;
      int cs = (((s & 7) ^ (r & 7)) << 3);
      async_load16(&A[(size_t)(row0 + r) * D_ + kt + cs], &As[j * 2048 + w * 512]);
      async_load16(&Bt[(size_t)(col0 + r) * D_ + kt + cs], &Bs[j * 2048 + w * 512]);
    }
    __syncthreads();
#pragma unroll
    for (int ks = 0; ks < BK; ks += 32) {
      const int go = ((lq + (ks >> 3)) ^ rx) << 3;
      bf16x8 af[4], bfr[4];
#pragma unroll
      for (int i = 0; i < 4; ++i)
        af[i] = *(const bf16x8*)&As[(wm + i * 16 + lr) * BK + go];
#pragma unroll
      for (int j = 0; j < 4; ++j)
        bfr[j] = *(const bf16x8*)&Bs[(wn + j * 16 + lr) * BK + go];
#pragma unroll
      for (int i = 0; i < 4; ++i)
#pragma unroll
        for (int j = 0; j < 4; ++j)
          acc[i][j] = __builtin_amdgcn_mfma_f32_16x16x32_bf16(af[i], bfr[j], acc[i][j], 0, 0, 0);
    }
    __syncthreads();
  }

#pragma unroll
  for (int i = 0; i < 4; ++i) {
#pragma unroll
    for (int j = 0; j < 4; ++j) {
      int gr = row0 + wm + i * 16 + lq * 4;
      int gc = col0 + wn + j * 16 + lr;
      float bsv = bias[gc];
#pragma unroll
      for (int r = 0; r < 4; ++r)
        outf[(size_t)(gr + r) * D_ + gc] = acc[i][j][r] + bsv;
    }
  }
}

// ---------------- KV summarize (MFMA): KVt[bh][e][d] += sum_s V[s][e]*K[s][d]; Ksum[bh][d] ----------------
#define KVP 68  // LDS row stride (elems) for transposed tiles
__global__ __launch_bounds__(256) void kv_mfma_kernel(
    const bf16_t* __restrict__ Kf, const bf16_t* __restrict__ Vf,
    float* __restrict__ KVtg, float* __restrict__ Ksumg) {
  __shared__ __attribute__((aligned(16))) bf16_t Kt[64 * KVP];  // [d][s]
  __shared__ __attribute__((aligned(16))) bf16_t Vt[64 * KVP];  // [e][s]
  const int t = threadIdx.x;
  const int w = t >> 6, lane = t & 63;
  const int lr = lane & 15, lq = lane >> 4;
  const int bh = blockIdx.x, sc = blockIdx.y;
  const int b = bh >> 4, h = bh & 15;
  const size_t base = (size_t)b * S_ * D_ + (size_t)h * HD_;
  const int p = t >> 3;          // row-pair 0..31
  const int c0 = (t & 7) * 8;    // feature col 0..56

  floatx4 acc[4], accn[4];
#pragma unroll
  for (int j = 0; j < 4; ++j) {
    acc[j] = (floatx4){0.f, 0.f, 0.f, 0.f};
    accn[j] = (floatx4){0.f, 0.f, 0.f, 0.f};
  }
  bf16x8 ones;
#pragma unroll
  for (int u = 0; u < 8; ++u) ones[u] = (bf16_t)(lr == 0 ? 1.f : 0.f);

  for (int st = 0; st < 8; ++st) {  // 8 tiles x 64 s = 512 s
    int s0 = sc * 512 + st * 64;
    bf16x8 ka = *(const bf16x8*)&Kf[base + (size_t)(s0 + 2 * p) * D_ + c0];
    bf16x8 kb = *(const bf16x8*)&Kf[base + (size_t)(s0 + 2 * p + 1) * D_ + c0];
    bf16x8 va = *(const bf16x8*)&Vf[base + (size_t)(s0 + 2 * p) * D_ + c0];
    bf16x8 vb = *(const bf16x8*)&Vf[base + (size_t)(s0 + 2 * p + 1) * D_ + c0];
    __syncthreads();  // previous iter's reads done before overwriting LDS
#pragma unroll
    for (int u = 0; u < 8; ++u) {
      *(bf16x2*)&Kt[(c0 + u) * KVP + 2 * p] = (bf16x2){ka[u], kb[u]};
      *(bf16x2*)&Vt[(c0 + u) * KVP + 2 * p] = (bf16x2){va[u], vb[u]};
    }
    __syncthreads();
#pragma unroll
    for (int ks = 0; ks < 2; ++ks) {
      bf16x8 af = *(const bf16x8*)&Vt[(w * 16 + lr) * KVP + ks * 32 + lq * 8];
      bf16x8 bf_[4];
#pragma unroll
      for (int j = 0; j < 4; ++j)
        bf_[j] = *(const bf16x8*)&Kt[(j * 16 + lr) * KVP + ks * 32 + lq * 8];
#pragma unroll
      for (int j = 0; j < 4; ++j)
        acc[j] = __builtin_amdgcn_mfma_f32_16x16x32_bf16(af, bf_[j], acc[j], 0, 0, 0);
      if (w == 0) {
#pragma unroll
        for (int j = 0; j < 4; ++j)
          accn[j] = __builtin_amdgcn_mfma_f32_16x16x32_bf16(ones, bf_[j], accn[j], 0, 0, 0);
      }
    }
  }
  float* kvp = KVtg + (size_t)bh * 4096;
#pragma unroll
  for (int j = 0; j < 4; ++j)
#pragma unroll
    for (int r = 0; r < 4; ++r)
      atomicAdd(&kvp[(w * 16 + lq * 4 + r) * 64 + j * 16 + lr], acc[j][r]);
  if (w == 0 && lq == 0) {
#pragma unroll
    for (int j = 0; j < 4; ++j)
      atomicAdd(&Ksumg[bh * 64 + j * 16 + lr], accn[j][0]);
  }
}

// ---------------- attend (MFMA): X[b,q,h,:] = (Q . KV) / (Q . Ksum + 1e-6) ----------------
// As/Bs XOR-swizzled at 16B-chunk granularity.
__global__ __launch_bounds__(256) void attend_mfma_kernel(
    const bf16_t* __restrict__ Qf, const float* __restrict__ KVtg,
    const float* __restrict__ Ksumg, bf16_t* __restrict__ X) {
  __shared__ __attribute__((aligned(16))) bf16_t As[256 * 64];  // 32KB
  __shared__ __attribute__((aligned(16))) bf16_t Bs[64 * 64];   // 8KB
  const int t = threadIdx.x;
  const int w = t >> 6;
  const int lane = t & 63;
  const int lr = lane & 15;
  const int lq = lane >> 4;
  const int rx = lr & 7;
  const int bh = blockIdx.y;
  const int b = bh >> 4, h = bh & 15;
  const int q0 = blockIdx.x * 256;
  const size_t qbase = ((size_t)b * S_ + q0) * D_ + (size_t)h * HD_;

  // stage Q rows via async LDS DMA (swizzled source chunk)
  {
    const int r8 = lane >> 3;
    const int cs = (((lane & 7) ^ (r8 & 7)) << 3);
#pragma unroll
    for (int it = 0; it < 8; ++it) {
      int r = w * 64 + it * 8 + r8;
      async_load16(&Qf[qbase + (size_t)r * D_ + cs], &As[(w * 64 + it * 8) * 64]);
    }
  }
  // stage KV^T: fp32 -> bf16 cast (KVtg is [e][d] row-major = exactly Bt layout), swizzled store
  {
    const float* src = KVtg + (size_t)bh * 4096;
    int i0 = t * 16;
    float4 f0 = *(const float4*)(src + i0);
    float4 f1 = *(const float4*)(src + i0 + 4);
    float4 f2 = *(const float4*)(src + i0 + 8);
    float4 f3 = *(const float4*)(src + i0 + 12);
    bf16x8 o1, o2;
    o1[0] = (bf16_t)f0.x; o1[1] = (bf16_t)f0.y; o1[2] = (bf16_t)f0.z; o1[3] = (bf16_t)f0.w;
    o1[4] = (bf16_t)f1.x; o1[5] = (bf16_t)f1.y; o1[6] = (bf16_t)f1.z; o1[7] = (bf16_t)f1.w;
    o2[0] = (bf16_t)f2.x; o2[1] = (bf16_t)f2.y; o2[2] = (bf16_t)f2.z; o2[3] = (bf16_t)f2.w;
    o2[4] = (bf16_t)f3.x; o2[5] = (bf16_t)f3.y; o2[6] = (bf16_t)f3.z; o2[7] = (bf16_t)f3.w;
    int r = t >> 2;
    int cc = (t & 3) * 2;
    int rxw = r & 7;
    *(bf16x8*)&Bs[r * 64 + ((cc ^ rxw) << 3)] = o1;
    *(bf16x8*)&Bs[r * 64 + (((cc + 1) ^ rxw) << 3)] = o2;
  }

  // norm B fragments: row n=0 holds Ksum (bf16), rows 1..15 zero
  bf16x8 bn[2];
#pragma unroll
  for (int ks = 0; ks < 2; ++ks) {
    bf16x8 z;
#pragma unroll
    for (int u = 0; u < 8; ++u) z[u] = (bf16_t)0.f;
    if (lr == 0) {
      const float* kp = &Ksumg[bh * 64 + ks * 32 + lq * 8];
      float4 k1 = *(const float4*)kp;
      float4 k2 = *(const float4*)(kp + 4);
      z[0] = (bf16_t)k1.x; z[1] = (bf16_t)k1.y; z[2] = (bf16_t)k1.z; z[3] = (bf16_t)k1.w;
      z[4] = (bf16_t)k2.x; z[5] = (bf16_t)k2.y; z[6] = (bf16_t)k2.z; z[7] = (bf16_t)k2.w;
    }
    bn[ks] = z;
  }

  floatx4 acc[4][4];
  floatx4 accn[4];
#pragma unroll
  for (int i = 0; i < 4; ++i) {
    accn[i] = (floatx4){0.f, 0.f, 0.f, 0.f};
#pragma unroll
    for (int j = 0; j < 4; ++j) acc[i][j] = (floatx4){0.f, 0.f, 0.f, 0.f};
  }

  __syncthreads();

#pragma unroll
  for (int ks = 0; ks < 2; ++ks) {
    // ks is a STEP INDEX here (chunk offset = ks*4)
    const int go = ((lq + ks * 4) ^ rx) << 3;
    bf16x8 af[4], bfr[4];
#pragma unroll
    for (int i = 0; i < 4; ++i)
      af[i] = *(const bf16x8*)&As[(w * 64 + i * 16 + lr) * 64 + go];
#pragma unroll
    for (int j = 0; j < 4; ++j)
      bfr[j] = *(const bf16x8*)&Bs[(j * 16 + lr) * 64 + go];
#pragma unroll
    for (int i = 0; i < 4; ++i) {
#pragma unroll
      for (int j = 0; j < 4; ++j)
        acc[i][j] = __builtin_amdgcn_mfma_f32_16x16x32_bf16(af[i], bfr[j], acc[i][j], 0, 0, 0);
      accn[i] = __builtin_amdgcn_mfma_f32_16x16x32_bf16(af[i], bn[ks], accn[i], 0, 0, 0);
    }
  }

  // epilogue: normalize and store bf16
#pragma unroll
  for (int i = 0; i < 4; ++i) {
    int rowb = q0 + w * 64 + i * 16 + lq * 4;
#pragma unroll
    for (int r = 0; r < 4; ++r) {
      float nr = __shfl(accn[i][r], lane & 48);  // norm lives on lane lr==0 of each lq group
      float inv = 1.f / (nr + 1e-6f);
      size_t rb = ((size_t)b * S_ + rowb + r) * D_ + (size_t)h * HD_;
#pragma unroll
      for (int j = 0; j < 4; ++j)
        X[rb + j * 16 + lr] = (bf16_t)(acc[i][j][r] * inv);
    }
  }
}

extern "C" void kernel_launch(void* const* d_in, const int* in_sizes, int n_in,
                              void* d_out, int out_size, void* d_ws, size_t ws_size,
                              hipStream_t stream) {
  const float* query     = (const float*)d_in[0];
  const float* key_value = (const float*)d_in[1];
  const float* Wq = (const float*)d_in[2];
  const float* bq = (const float*)d_in[3];
  const float* Wk = (const float*)d_in[4];
  const float* bk = (const float*)d_in[5];
  const float* Wv = (const float*)d_in[6];
  const float* bv = (const float*)d_in[7];
  const float* Wo = (const float*)d_in[8];
  const float* bo = (const float*)d_in[9];
  float* out = (float*)d_out;

  char* ws = (char*)d_ws;
  const size_t MB = 1024 * 1024;
  bf16_t* Aq   = (bf16_t*)(ws + 0);         // 32MB (query bf16; later reused as X)
  bf16_t* Akv  = (bf16_t*)(ws + 32 * MB);   // 32MB (key_value bf16)
  bf16_t* WqT  = (bf16_t*)(ws + 64 * MB);   // 2MB each
  bf16_t* WkT  = (bf16_t*)(ws + 66 * MB);   // WkT and WvT ADJACENT -> fused N=2048 B matrix
  bf16_t* WvT  = (bf16_t*)(ws + 68 * MB);
  bf16_t* WoT  = (bf16_t*)(ws + 70 * MB);
  bf16_t* Qf   = (bf16_t*)(ws + 72 * MB);   // 32MB
  bf16_t* Kf   = (bf16_t*)(ws + 104 * MB);  // 32MB
  bf16_t* Vf   = (bf16_t*)(ws + 136 * MB);  // 32MB
  float*  KVtg = (float*)(ws + 168 * MB);   // 1MB  (64 x [e][d] fp32)
  float*  Ksumg= (float*)(ws + 169 * MB);   // 16KB (contiguous after KVtg)

  // 1) prep: casts + transposes + zeroing, one launch
  PrepArgs pa = {query, key_value, Aq, Akv, Wq, Wk, Wv, Wo, WqT, WkT, WvT, WoT, KVtg};
  prep_kernel<<<20740, 256, 0, stream>>>(pa);

  // 2) merged Q/K/V projection GEMM
  ProjArgs pj = {Aq, Akv, WqT, WkT, bq, bk, bv, Qf, Kf, Vf};
  proj_kernel<<<3072, 256, 0, stream>>>(pj);

  // 3) KV summarize
  dim3 kvgrid(64, 8);
  kv_mfma_kernel<<<kvgrid, 256, 0, stream>>>(Kf, Vf, KVtg, Ksumg);

  // 4) attend
  dim3 agrid(S_ / 256, 64);  // (16, 64)
  attend_mfma_kernel<<<agrid, 256, 0, stream>>>(Qf, KVtg, Ksumg, Aq /* X */);

  // 5) output projection
  dim3 ggrid(D_ / BN, M_TOT / BM);  // (8, 128)
  gemm_out_kernel<<<ggrid, 256, 0, stream>>>(Aq, WoT, bo, out);
}